// Round 20
// baseline (30.617 us; speedup 1.0000x reference)
//
#include <hip/hip_runtime.h>
#include <math.h>

#define TWO_PI_F 6.28318530717958647692f

typedef unsigned int u32;
typedef __attribute__((ext_vector_type(4))) float    f4;
typedef __attribute__((ext_vector_type(16))) float   f16v;
typedef __attribute__((ext_vector_type(2))) float    f2;
typedef __attribute__((ext_vector_type(2))) _Float16 h2;
typedef __attribute__((ext_vector_type(4))) _Float16 h4;
typedef __attribute__((ext_vector_type(8))) _Float16 h8;

union B8 { h8 v; h4 q[2]; };
union C2 { u32 w[2]; h4 v; };
union P4 { h2 a[4]; h8 v; };

#if __has_builtin(__builtin_amdgcn_cvt_pkrtz)
__device__ __forceinline__ h2 CVTPK(float a, float b) {
    return __builtin_bit_cast(h2, __builtin_amdgcn_cvt_pkrtz(a, b));
}
#else
__device__ __forceinline__ h2 CVTPK(float a, float b) {
    return (h2){(_Float16)a, (_Float16)b};
}
#endif

// ---------------------------------------------------------------------------
// 64x64 tile per block (528 triangular blocks, 512 threads = 8 waves):
// 4x work per block amortizes setup/barriers/ramp 4x vs the 32x32 version
// whose ~1us blocks left CUs under-resident (occupancy 15%, waves solo).
// Math identical to r19: p(h,v) via mfma_f32_32x32x16_f16 (K=16 exact),
// orientation swap on the A side (o = wv>>2 wave-invariant), relu-split
// epilogue (|src| fma + separable linear term).
// Wave wv handles il in [(wv&3)*16, +16), both 32-col halves per iter
// (dual stream A/B share the row pe and L-row; both bq1 halves invariant).
// ---------------------------------------------------------------------------
__global__ __launch_bounds__(512, 4) void gd_mfma(
    const float* __restrict__ z,  const float* __restrict__ s,
    const float* __restrict__ W1, const float* __restrict__ b1,
    const float* __restrict__ W2, const float* __restrict__ b2v,
    float* __restrict__ out, int N, int NB)
{
    __shared__ __attribute__((aligned(16))) _Float16 Ald[64][24]; // 3KB
    __shared__ __attribute__((aligned(16))) h4 peb[128];          // 1KB
    __shared__ __attribute__((aligned(16))) h2 P2[4096];          // 16KB {ct,st}
    __shared__ __attribute__((aligned(16))) float S[2][64][68];   // 34.8KB
    __shared__ __attribute__((aligned(16))) f4 strig2[128];       // 2KB
    __shared__ __attribute__((aligned(16))) float w2f[64];        // 256B
    __shared__ float Lp[12];
    __shared__ float LA[128], LB[128];                            // 1KB

    // --- triangular block decode: u -> (bi, bj), bj >= bi ---
    int u = blockIdx.x;
    int M = 2 * NB + 1;
    float disc = (float)(M * M - 8 * u);
    int bi = (int)(((float)M - sqrtf(disc)) * 0.5f);
    if (bi < 0) bi = 0;
    if (bi > NB - 1) bi = NB - 1;
    while (bi > 0 && bi * (M - bi) / 2 > u) --bi;
    while ((bi + 1) * (M - (bi + 1)) / 2 <= u) ++bi;
    int bj = bi + (u - bi * (M - bi) / 2);

    int t    = threadIdx.x;
    int lane = t & 63;

    // --- setup: t<128 trig rows; wave 0 additionally V^T rows + Lp ---
    if (t < 128) {
        int grow = (t < 64) ? (bi * 64 + t) : (bj * 64 + (t - 64));
        float ang = TWO_PI_F * s[grow];
        float c1 = __cosf(ang), s1 = __sinf(ang);
        float c2 = c1 * c1 - s1 * s1, s2 = 2.0f * c1 * s1;
        strig2[t] = (f4){c1, s1, c2, s2};
        peb[t]    = (h4){(_Float16)c1, (_Float16)s1, (_Float16)c2, (_Float16)s2};
    }
    if (t < 64) {
        float w2t = W2[t];
        w2f[t] = w2t;

        float zc = b1[t];
#pragma unroll
        for (int zz = 0; zz < 32; ++zz)
            zc = fmaf(z[zz], W1[(10 + zz) * 64 + t], zc);

        h8 row0, row1;
#pragma unroll
        for (int k = 0; k < 8; ++k) row0[k] = (_Float16)W1[k * 64 + t];
        row1 = (h8)0;
        row1[0] = (_Float16)W1[8 * 64 + t];   // wc
        row1[1] = (_Float16)W1[9 * 64 + t];   // ws
        row1[2] = (_Float16)zc;               // bias via "1" feature
        *(h8*)&Ald[t][0] = row0;
        *(h8*)&Ald[t][8] = row1;

        // Lp[k] = 0.25 * sum_h V[k,h]*w2[h] : 64-lane butterfly (wave 0)
        float q25 = 0.25f * w2t;
        float lv[11];
#pragma unroll
        for (int k = 0; k < 8; ++k) lv[k] = (float)row0[k] * q25;
        lv[8]  = (float)row1[0] * q25;
        lv[9]  = (float)row1[1] * q25;
        lv[10] = zc * q25;
#pragma unroll
        for (int off = 32; off; off >>= 1)
#pragma unroll
            for (int k = 0; k < 11; ++k)
                lv[k] += __shfl_xor(lv[k], off);
        if (t == 0) {
#pragma unroll
            for (int k = 0; k < 11; ++k) Lp[k] = lv[k];
        }
    }
    __syncthreads();

    // --- P2 build (8 cells/thread, one b128 store) + LA/LB (t<128) ---
    {
        int il = t >> 3;
        int j0 = (t & 7) * 8;
        f4 ci = strig2[il];
#pragma unroll
        for (int g = 0; g < 2; ++g) {
            P4 pk;
#pragma unroll
            for (int c = 0; c < 4; ++c) {
                f4 cj = strig2[64 + j0 + g * 4 + c];
                float ctv = fmaf(ci.x, cj.x, ci.y * cj.y);
                float stv = fabsf(fmaf(ci.y, cj.x, -(ci.x * cj.y)));
                pk.a[c] = CVTPK(ctv, stv);
            }
            *(h8*)&P2[il * 64 + j0 + g * 4] = pk.v;
        }
    }
    if (t < 128) {
        f4 tg = strig2[t];
        LA[t] = fmaf(Lp[0], tg.x, fmaf(Lp[1], tg.y,
                 fmaf(Lp[2], tg.z, fmaf(Lp[3], tg.w, Lp[10]))));
        LB[t] = fmaf(Lp[4], tg.x, fmaf(Lp[5], tg.y,
                 fmaf(Lp[6], tg.z, Lp[7] * tg.w)));
    }

    int n  = lane & 31;
    int q  = lane >> 5;
    int wv = t >> 6;
    int o  = wv >> 2;            // orientation: wave-invariant

    // 0.25*w2 f32 registers matched to C row layout
    float w2v[2][16];
#pragma unroll
    for (int H = 0; H < 2; ++H)
#pragma unroll
        for (int e = 0; e < 16; ++e)
            w2v[H][e] = 0.25f * w2f[(e & 3) + 8 * (e >> 2) + 4 * q + 32 * H];

    // A-frags: o=1 waves swap the k0..3 / k4..7 halves (orientation on A side)
    h8 afr[2];
#pragma unroll
    for (int H = 0; H < 2; ++H) {
        int hh = H * 32 + n;
        B8 af;
        if (q == 0) {
            af.q[0] = *(const h4*)&Ald[hh][o ? 4 : 0];
            af.q[1] = *(const h4*)&Ald[hh][o ? 0 : 4];
        } else {
            af.v = *(const h8*)&Ald[hh][8];
        }
        afr[H] = af.v;
    }
    __syncthreads();

    // --- phase 2: 16 il-rows per wave, both 32-col halves per iteration ---
    int il0 = (wv & 3) * 16;

    h4 pe_col0 = peb[64 + n];               // col pe, half 0 (invariant)
    h4 pe_col1 = peb[96 + n];               // col pe, half 1 (invariant)
    h4 bq1A    = q ? (h4)0 : pe_col0;       // B-frag half 2: FULLY invariant
    h4 bq1B    = q ? (h4)0 : pe_col1;
    const float* Lrow = o ? LB : LA;        // hoisted wave-uniform selects
    const float* Lcol = o ? LA : LB;
    float laneInvA = Lcol[64 + n];
    float laneInvB = Lcol[96 + n];
    float Lp8r = Lp[8], Lp9r = Lp[9];

#pragma unroll
    for (int i = 0; i < 16; ++i) {
        int il = il0 + i;

        h4 var = peb[il];                          // broadcast (uniform addr)
        u32 pwA = *(const u32*)&P2[il * 64 + n];   // conflict-free b32
        u32 pwB = *(const u32*)&P2[il * 64 + 32 + n];
        float row = Lrow[il];                      // uniform broadcast read

        B8 bA, bB;
        C2 ccA; ccA.w[0] = pwA; ccA.w[1] = 0x00003C00u;   // {ct,st,1,0}
        C2 ccB; ccB.w[0] = pwB; ccB.w[1] = 0x00003C00u;
        bA.q[0] = q ? ccA.v : var;
        bA.q[1] = bq1A;
        bB.q[0] = q ? ccB.v : var;
        bB.q[1] = bq1B;

        f16v a0A = __builtin_amdgcn_mfma_f32_32x32x16_f16(afr[0], bA.v, (f16v)(0.0f), 0, 0, 0);
        f16v a1A = __builtin_amdgcn_mfma_f32_32x32x16_f16(afr[1], bA.v, (f16v)(0.0f), 0, 0, 0);
        f16v a0B = __builtin_amdgcn_mfma_f32_32x32x16_f16(afr[0], bB.v, (f16v)(0.0f), 0, 0, 0);
        f16v a1B = __builtin_amdgcn_mfma_f32_32x32x16_f16(afr[1], bB.v, (f16v)(0.0f), 0, 0, 0);

        float cA0 = 0.f, cA1 = 0.f, cA2 = 0.f, cA3 = 0.f;
        float cB0 = 0.f, cB1 = 0.f, cB2 = 0.f, cB3 = 0.f;
#pragma unroll
        for (int e = 0; e < 8; ++e) {      // |src| is a free VOP3 modifier
            cA0 = fmaf(fabsf(a0A[e]),     w2v[0][e],     cA0);
            cA1 = fmaf(fabsf(a0A[e + 8]), w2v[0][e + 8], cA1);
            cA2 = fmaf(fabsf(a1A[e]),     w2v[1][e],     cA2);
            cA3 = fmaf(fabsf(a1A[e + 8]), w2v[1][e + 8], cA3);
            cB0 = fmaf(fabsf(a0B[e]),     w2v[0][e],     cB0);
            cB1 = fmaf(fabsf(a0B[e + 8]), w2v[0][e + 8], cB1);
            cB2 = fmaf(fabsf(a1B[e]),     w2v[1][e],     cB2);
            cB3 = fmaf(fabsf(a1B[e + 8]), w2v[1][e + 8], cB3);
        }
        float psA = (cA0 + cA1) + (cA2 + cA3);
        float psB = (cB0 + cB1) + (cB2 + cB3);
        psA += __shfl_xor(psA, 32);        // abs part: combine the two K-halves
        psB += __shfl_xor(psB, 32);

        // linear part (exact matmul identity, separable)
        h2 ppA = __builtin_bit_cast(h2, pwA);
        h2 ppB = __builtin_bit_cast(h2, pwB);
        float linA = row + laneInvA;
        linA = fmaf((float)ppA[0], Lp8r, linA);
        linA = fmaf((float)ppA[1], Lp9r, linA);
        float linB = row + laneInvB;
        linB = fmaf((float)ppB[0], Lp8r, linB);
        linB = fmaf((float)ppB[1], Lp9r, linB);
        psA += linA;
        psB += linB;

        if (q == 0) {
            S[o][il][n]      = psA;
            S[o][il][32 + n] = psB;
        }
    }
    __syncthreads();

    // --- phase 3: symmetrized output + mirror (coalesced f4 stores) ---
    float b2 = b2v[0];
    {
        int il = t >> 3;
        int j0 = (t & 7) * 8;
#pragma unroll
        for (int g = 0; g < 2; ++g) {
            int jb = j0 + g * 4;
            f4 a = *(const f4*)&S[0][il][jb];
            f4 b = *(const f4*)&S[1][il][jb];
            f4 v;
#pragma unroll
            for (int c = 0; c < 4; ++c) {
                float x = a[c] + b[c] + b2;
                if (bi == bj && il == jb + c) x = -1e9f;
                v[c] = x;
            }
            *(f4*)&out[(size_t)(bi * 64 + il) * N + bj * 64 + jb] = v;
        }

        if (bj > bi) {
            int jl = t >> 3;
            int i0 = (t & 7) * 8;
#pragma unroll
            for (int g = 0; g < 2; ++g) {
                int ib = i0 + g * 4;
                f4 m;
#pragma unroll
                for (int c = 0; c < 4; ++c)
                    m[c] = S[0][ib + c][jl] + S[1][ib + c][jl] + b2;
                *(f4*)&out[(size_t)(bj * 64 + jl) * N + bi * 64 + ib] = m;
            }
        }
    }
}

extern "C" void kernel_launch(void* const* d_in, const int* in_sizes, int n_in,
                              void* d_out, int out_size, void* d_ws, size_t ws_size,
                              hipStream_t stream) {
    const float* z  = (const float*)d_in[0];  // [32]
    const float* s  = (const float*)d_in[1];  // [N]
    const float* W1 = (const float*)d_in[2];  // [42,64]
    const float* b1 = (const float*)d_in[3];  // [64]
    const float* W2 = (const float*)d_in[4];  // [64]
    const float* b2 = (const float*)d_in[5];  // [1]
    int N = in_sizes[1];                      // 2048

    float* out = (float*)d_out;
    int NB = N / 64;
    int nblk = NB * (NB + 1) / 2;             // 528 for N=2048
    gd_mfma<<<nblk, 512, 0, stream>>>(z, s, W1, b1, W2, b2, out, N, NB);
}

// Round 21
// 27.055 us; speedup vs baseline: 1.1317x; 1.1317x over previous
//
#include <hip/hip_runtime.h>
#include <math.h>

#define TWO_PI_F 6.28318530717958647692f

typedef unsigned int u32;
typedef __attribute__((ext_vector_type(4))) float    f4;
typedef __attribute__((ext_vector_type(16))) float   f16v;
typedef __attribute__((ext_vector_type(2))) float    f2;
typedef __attribute__((ext_vector_type(2))) _Float16 h2;
typedef __attribute__((ext_vector_type(4))) _Float16 h4;
typedef __attribute__((ext_vector_type(8))) _Float16 h8;

union B8 { h8 v; h4 q[2]; };
union C2 { u32 w[2]; h4 v; };
union P4 { h2 a[4]; h8 v; };

#if __has_builtin(__builtin_amdgcn_cvt_pkrtz)
__device__ __forceinline__ h2 CVTPK(float a, float b) {
    return __builtin_bit_cast(h2, __builtin_amdgcn_cvt_pkrtz(a, b));
}
#else
__device__ __forceinline__ h2 CVTPK(float a, float b) {
    return (h2){(_Float16)a, (_Float16)b};
}
#endif

// ---------------------------------------------------------------------------
// r19 structure (best measured: 27.02 us) + __launch_bounds__(256,2):
// lifts VGPR cap ~170 -> 256 so the compiler can keep 4 live f16v C-frags
// (64 VGPRs) AND pipeline iteration n+1's MFMAs under iteration n's epilogue.
// Math: p(h,v) via mfma_f32_32x32x16_f16 (K=16 exact), orientation swap on
// the A side (o = wv>>1 wave-invariant -> B-frag half 2 iteration-invariant),
// relu-split epilogue: abs part via |src| fma (free VOP3 modifier), linear
// part separable (LA/LB rows + Lp8/Lp9 in-register).
// 2080 upper-triangular 32x32 blocks, 256 threads, 4 MFMAs/iter dual-stream.
// ---------------------------------------------------------------------------
__global__ __launch_bounds__(256, 2) void gd_mfma(
    const float* __restrict__ z,  const float* __restrict__ s,
    const float* __restrict__ W1, const float* __restrict__ b1,
    const float* __restrict__ W2, const float* __restrict__ b2v,
    float* __restrict__ out, int N, int NB)
{
    __shared__ __attribute__((aligned(16))) _Float16 Ald[64][24]; // 3KB
    __shared__ __attribute__((aligned(16))) h4 peb[64];           // 512B
    __shared__ __attribute__((aligned(16))) h2 P2[1024];          // 4KB {ct,st}
    __shared__ __attribute__((aligned(16))) float S[2][32][36];   // 9.2KB
    __shared__ __attribute__((aligned(16))) f4 strig2[64];        // 1KB
    __shared__ __attribute__((aligned(16))) float w2f[64];        // 256B
    __shared__ float Lp[12];                                      // 48B
    __shared__ float LA[64], LB[64];                              // 512B

    // --- triangular block decode: u -> (bi, bj), bj >= bi ---
    int u = blockIdx.x;
    int M = 2 * NB + 1;
    float disc = (float)(M * M - 8 * u);
    int bi = (int)(((float)M - sqrtf(disc)) * 0.5f);
    if (bi < 0) bi = 0;
    if (bi > NB - 1) bi = NB - 1;
    while (bi > 0 && bi * (M - bi) / 2 > u) --bi;
    while ((bi + 1) * (M - (bi + 1)) / 2 <= u) ++bi;
    int bj = bi + (u - bi * (M - bi) / 2);

    int t    = threadIdx.x;
    int lane = t & 63;

    if (t < 64) {                        // wave 0: trig + pe + V^T rows + Lp
        int grow = (t < 32) ? (bi * 32 + t) : (bj * 32 + (t - 32));
        float ang = TWO_PI_F * s[grow];
        float c1 = __cosf(ang), s1 = __sinf(ang);
        float c2 = c1 * c1 - s1 * s1, s2 = 2.0f * c1 * s1;
        strig2[t] = (f4){c1, s1, c2, s2};
        peb[t]    = (h4){(_Float16)c1, (_Float16)s1, (_Float16)c2, (_Float16)s2};
        float w2t = W2[t];
        w2f[t] = w2t;

        float zc = b1[t];
#pragma unroll
        for (int zz = 0; zz < 32; ++zz)
            zc = fmaf(z[zz], W1[(10 + zz) * 64 + t], zc);

        h8 row0, row1;
#pragma unroll
        for (int k = 0; k < 8; ++k) row0[k] = (_Float16)W1[k * 64 + t];
        row1 = (h8)0;
        row1[0] = (_Float16)W1[8 * 64 + t];   // wc
        row1[1] = (_Float16)W1[9 * 64 + t];   // ws
        row1[2] = (_Float16)zc;               // bias via "1" feature
        *(h8*)&Ald[t][0] = row0;
        *(h8*)&Ald[t][8] = row1;

        // Lp[k] = 0.25 * sum_h V[k,h]*w2[h] : 64-lane butterfly (wave 0)
        float q25 = 0.25f * w2t;
        float lv[11];
#pragma unroll
        for (int k = 0; k < 8; ++k) lv[k] = (float)row0[k] * q25;
        lv[8]  = (float)row1[0] * q25;
        lv[9]  = (float)row1[1] * q25;
        lv[10] = zc * q25;
#pragma unroll
        for (int off = 32; off; off >>= 1)
#pragma unroll
            for (int k = 0; k < 11; ++k)
                lv[k] += __shfl_xor(lv[k], off);
        if (t == 0) {
#pragma unroll
            for (int k = 0; k < 11; ++k) Lp[k] = lv[k];
        }
    }
    __syncthreads();

    // --- P2 build (all threads) + LA/LB rows (t<64) ---
    {
        int base = t * 4;
        int il = base >> 5, j0 = base & 31;
        f4 ci = strig2[il];
        P4 pk;
#pragma unroll
        for (int c = 0; c < 4; ++c) {
            f4 cj = strig2[32 + j0 + c];
            float ctv = fmaf(ci.x, cj.x, ci.y * cj.y);
            float stv = fabsf(fmaf(ci.y, cj.x, -(ci.x * cj.y)));
            pk.a[c] = CVTPK(ctv, stv);
        }
        *(h8*)&P2[base] = pk.v;
    }
    if (t < 64) {
        f4 tg = strig2[t];
        LA[t] = fmaf(Lp[0], tg.x, fmaf(Lp[1], tg.y,
                 fmaf(Lp[2], tg.z, fmaf(Lp[3], tg.w, Lp[10]))));
        LB[t] = fmaf(Lp[4], tg.x, fmaf(Lp[5], tg.y,
                 fmaf(Lp[6], tg.z, Lp[7] * tg.w)));
    }

    int n  = lane & 31;
    int q  = lane >> 5;
    int wv = t >> 6;
    int o  = wv >> 1;            // orientation: wave-invariant

    // 0.25*w2 f32 registers matched to C row layout
    float w2v[2][16];
#pragma unroll
    for (int H = 0; H < 2; ++H)
#pragma unroll
        for (int e = 0; e < 16; ++e)
            w2v[H][e] = 0.25f * w2f[(e & 3) + 8 * (e >> 2) + 4 * q + 32 * H];
    __syncthreads();

    // A-frags: o=1 waves swap the k0..3 / k4..7 halves (orientation on A side)
    h8 afr[2];
#pragma unroll
    for (int H = 0; H < 2; ++H) {
        int hh = H * 32 + n;
        B8 af;
        if (q == 0) {
            af.q[0] = *(const h4*)&Ald[hh][o ? 4 : 0];
            af.q[1] = *(const h4*)&Ald[hh][o ? 0 : 4];
        } else {
            af.v = *(const h8*)&Ald[hh][8];
        }
        afr[H] = af.v;
    }

    // --- phase 2: dual-stream MFMA loop, o-free B-frags ---
    int base = (wv & 1) * 16;    // il base

    h4 pe_col = peb[32 + n];                 // lane's column pe (invariant)
    h4 bq1    = q ? (h4)0 : pe_col;          // B-frag half 2: FULLY invariant
    const float* Lrow = o ? LB : LA;         // hoisted wave-uniform selects
    float laneInv = o ? LA[32 + n] : LB[32 + n];
    float Lp8r = Lp[8], Lp9r = Lp[9];

#pragma unroll
    for (int i = 0; i < 8; ++i) {
        int ilA = base + i;
        int ilB = base + i + 8;

        h4 varA = peb[ilA];                        // broadcast (uniform addr)
        h4 varB = peb[ilB];
        u32 pwA = *(const u32*)&P2[ilA * 32 + n];  // conflict-free b32
        u32 pwB = *(const u32*)&P2[ilB * 32 + n];
        float rowA = Lrow[ilA];                    // uniform broadcast reads
        float rowB = Lrow[ilB];

        B8 bA, bB;
        C2 ccA; ccA.w[0] = pwA; ccA.w[1] = 0x00003C00u;   // {ct,st,1,0}
        C2 ccB; ccB.w[0] = pwB; ccB.w[1] = 0x00003C00u;
        bA.q[0] = q ? ccA.v : varA;
        bA.q[1] = bq1;
        bB.q[0] = q ? ccB.v : varB;
        bB.q[1] = bq1;

        f16v a0A = __builtin_amdgcn_mfma_f32_32x32x16_f16(afr[0], bA.v, (f16v)(0.0f), 0, 0, 0);
        f16v a1A = __builtin_amdgcn_mfma_f32_32x32x16_f16(afr[1], bA.v, (f16v)(0.0f), 0, 0, 0);
        f16v a0B = __builtin_amdgcn_mfma_f32_32x32x16_f16(afr[0], bB.v, (f16v)(0.0f), 0, 0, 0);
        f16v a1B = __builtin_amdgcn_mfma_f32_32x32x16_f16(afr[1], bB.v, (f16v)(0.0f), 0, 0, 0);

        float cA0 = 0.f, cA1 = 0.f, cA2 = 0.f, cA3 = 0.f;
        float cB0 = 0.f, cB1 = 0.f, cB2 = 0.f, cB3 = 0.f;
#pragma unroll
        for (int e = 0; e < 8; ++e) {      // |src| is a free VOP3 modifier
            cA0 = fmaf(fabsf(a0A[e]),     w2v[0][e],     cA0);
            cA1 = fmaf(fabsf(a0A[e + 8]), w2v[0][e + 8], cA1);
            cA2 = fmaf(fabsf(a1A[e]),     w2v[1][e],     cA2);
            cA3 = fmaf(fabsf(a1A[e + 8]), w2v[1][e + 8], cA3);
            cB0 = fmaf(fabsf(a0B[e]),     w2v[0][e],     cB0);
            cB1 = fmaf(fabsf(a0B[e + 8]), w2v[0][e + 8], cB1);
            cB2 = fmaf(fabsf(a1B[e]),     w2v[1][e],     cB2);
            cB3 = fmaf(fabsf(a1B[e + 8]), w2v[1][e + 8], cB3);
        }
        float psA = (cA0 + cA1) + (cA2 + cA3);
        float psB = (cB0 + cB1) + (cB2 + cB3);
        psA += __shfl_xor(psA, 32);        // abs part: combine the two K-halves
        psB += __shfl_xor(psB, 32);

        // linear part (exact matmul identity, separable)
        h2 ppA = __builtin_bit_cast(h2, pwA);
        h2 ppB = __builtin_bit_cast(h2, pwB);
        float linA = rowA + laneInv;
        linA = fmaf((float)ppA[0], Lp8r, linA);
        linA = fmaf((float)ppA[1], Lp9r, linA);
        float linB = rowB + laneInv;
        linB = fmaf((float)ppB[0], Lp8r, linB);
        linB = fmaf((float)ppB[1], Lp9r, linB);
        psA += linA;
        psB += linB;

        if (q == 0) {
            S[o][ilA][n] = psA;
            S[o][ilB][n] = psB;
        }
    }
    __syncthreads();

    // --- phase 3: symmetrized output + mirror (coalesced f4 stores) ---
    float b2 = b2v[0];
    {
        int il = t >> 3;
        int j0 = (t & 7) * 4;
        f4 a = *(const f4*)&S[0][il][j0];
        f4 b = *(const f4*)&S[1][il][j0];
        f4 v;
#pragma unroll
        for (int c = 0; c < 4; ++c) {
            float x = a[c] + b[c] + b2;
            if (bi == bj && il == j0 + c) x = -1e9f;
            v[c] = x;
        }
        *(f4*)&out[(size_t)(bi * 32 + il) * N + bj * 32 + j0] = v;

        if (bj > bi) {
            int jl = t >> 3;
            int i0 = (t & 7) * 4;
            f4 m;
#pragma unroll
            for (int c = 0; c < 4; ++c)
                m[c] = S[0][i0 + c][jl] + S[1][i0 + c][jl] + b2;
            *(f4*)&out[(size_t)(bj * 32 + jl) * N + bi * 32 + i0] = m;
        }
    }
}

extern "C" void kernel_launch(void* const* d_in, const int* in_sizes, int n_in,
                              void* d_out, int out_size, void* d_ws, size_t ws_size,
                              hipStream_t stream) {
    const float* z  = (const float*)d_in[0];  // [32]
    const float* s  = (const float*)d_in[1];  // [N]
    const float* W1 = (const float*)d_in[2];  // [42,64]
    const float* b1 = (const float*)d_in[3];  // [64]
    const float* W2 = (const float*)d_in[4];  // [64]
    const float* b2 = (const float*)d_in[5];  // [1]
    int N = in_sizes[1];                      // 2048

    float* out = (float*)d_out;
    int NB = N / 32;
    int nblk = NB * (NB + 1) / 2;             // 2080 for N=2048
    gd_mfma<<<nblk, 256, 0, stream>>>(z, s, W1, b1, W2, b2, out, N, NB);
}